// Round 1
// baseline (665.854 us; speedup 1.0000x reference)
//
#include <hip/hip_runtime.h>
#include <stdint.h>

// SparseMoE gfx950, Round 6.
// R5 evidence: all 3 GEMMs ~116-120us at MfmaUtil 13%, HBM 15-25%, Occ 21-28%
// -> latency-bound (4-5x over both rooflines). The 2-barrier non-prefetched
// k-loop serializes global-load latency with MFMA at 2-2.5 blocks/CU.
// This round:
//  (1) Double-buffered LDS + prefetch k-loop (1 barrier/k-step): A-tile DMA and
//      B fp32 loads for tile t+1 issued BEFORE tile t's MFMAs; B convert+ds_write
//      after the MFMAs (issue-early/write-late).
//  (2) Router GEMM reads rw1 fp32 directly (BPATH=2: k' in [0,3072) -> [wh|wh|wl]);
//      the 3 transp_conv launches and RW1t staging are deleted.
typedef unsigned short ushort_t;
typedef __attribute__((ext_vector_type(8))) short short8;
typedef __attribute__((ext_vector_type(4))) float f32x4;

#define EMBED   1024
#define DFF     4096
#define NEXP    8
#define TOKENS  2048
#define SLOTS   4096
#define TMAX    40    // >= max Sum_e ceil(cnt_e/128) = 32+7 = 39

__device__ __forceinline__ ushort_t f2bf(float f) {
  unsigned u = __float_as_uint(f);
  u += 0x7FFFu + ((u >> 16) & 1u);   // RNE
  return (ushort_t)(u >> 16);
}
__device__ __forceinline__ float bf2f(ushort_t b) {
  return __uint_as_float(((unsigned)b) << 16);
}

// async 16B/lane global->LDS DMA. LDS dest wave-uniform; lane i lands at +16*i.
__device__ __forceinline__ void gl2lds16(const void* g, void* l) {
  typedef const __attribute__((address_space(1))) unsigned char* gp_t;
  typedef __attribute__((address_space(3))) unsigned char* lp_t;
  __builtin_amdgcn_global_load_lds((gp_t)(uintptr_t)g, (lp_t)(uintptr_t)l, 16, 0, 0);
}

__global__ void zero_small(int* counts, int* cursors) {
  int i = threadIdx.x;
  if (i < NEXP) { counts[i] = 0; cursors[i] = 0; }
}

// x [2048,1024] f32 -> Xs3 [2048,3072] bf16 : [xh | xl | xh]
__global__ void split_x3(const float* __restrict__ x, ushort_t* __restrict__ Xs) {
  int t = blockIdx.x;
  int d = threadIdx.x * 4;
  float4 v = *(const float4*)(x + (size_t)t * EMBED + d);
  ushort4 hi, lo;
  hi.x = f2bf(v.x); lo.x = f2bf(v.x - bf2f(hi.x));
  hi.y = f2bf(v.y); lo.y = f2bf(v.y - bf2f(hi.y));
  hi.z = f2bf(v.z); lo.z = f2bf(v.z - bf2f(hi.z));
  hi.w = f2bf(v.w); lo.w = f2bf(v.w - bf2f(hi.w));
  ushort_t* row = Xs + (size_t)t * 3072;
  *(ushort4*)(row + d)        = hi;
  *(ushort4*)(row + 1024 + d) = lo;
  *(ushort4*)(row + 2048 + d) = hi;
}

// ---------------- MFMA GEMM ----------------
// 128x128 tile, BK=32, 4 waves 2x2, 4x4 mfma_16x16x32_bf16.
// Double-buffered LDS (2x 128x32 per operand), chunk-XOR swizzle
// slot(q,row)=q^((row>>1)&3). ONE barrier per k-step; tile t+1 loads issued
// before tile t's MFMAs (A via global_load_lds DMA; B fp32 via regs,
// convert+ds_write after the MFMAs).
// EXPERT: 1-D grid, bid = xi + NX*(kc + SPLITK*t); (e,y) from compacted tile list.
//   t-blocks sharing a B chunk are NX*SPLITK apart (mult of 8 -> same XCD under id%8).
// BPATH 0: B bf16 [n][k] via async DMA.
//       1: B fp32 [k][n], reg-staged transpose+convert.
//       2: router split — B fp32 rw1 [1024][N]; k'<2048 -> wh(row k'&1023),
//          k'>=2048 -> wl(row k'-2048).  (pairs with A = Xs3 [xh|xl|xh])
// OUTMODE 0: f32 store [slot][c]. 1: bf16 store [slot][c].
//         3: f32 gated partial store [kc][slot][c] (bias folded on kc==0).
template<int BPATH, int OUTMODE, bool RELU, bool EXPERT, int SPLITK, int NX>
__global__ __launch_bounds__(256, 3)
void gemm_kernel(const ushort_t* __restrict__ A, const void* __restrict__ Bv,
                 const float* __restrict__ bias, void* __restrict__ Cout,
                 const float* __restrict__ slot_gate,
                 const int* __restrict__ off, const int* __restrict__ tile_e,
                 const int* __restrict__ tile_y, int M, int N, int K)
{
  __shared__ ushort_t As[2][128 * 32];
  __shared__ ushort_t Bs[2][128 * 32];

  int e = 0, kc = 0, row0, col0, m_base, m_cnt;
  if (EXPERT) {
    int bid  = blockIdx.x;
    int xi   = bid % NX;
    int rest = bid / NX;
    kc       = rest % SPLITK;
    int t    = rest / SPLITK;
    e = tile_e[t];
    if (e < 0) return;                    // padded tail, uniform exit
    row0   = tile_y[t] * 128;
    col0   = xi * 128;
    m_base = off[e];
    m_cnt  = off[e + 1] - m_base;
  } else {
    row0 = blockIdx.y * 128;
    col0 = blockIdx.x * 128;
    m_base = 0; m_cnt = M;
    if (row0 >= m_cnt) return;
  }
  const int Kc   = K / SPLITK;
  const int kbeg = kc * Kc;

  const int tid  = threadIdx.x;
  const int lane = tid & 63;
  const int wid  = tid >> 6;
  const int wm = wid & 1, wn = wid >> 1;

  // staging lane constants (DMA): lane i -> tile row base+(i>>2), slot i&3,
  // fetched global chunk = (i&3) ^ ((i>>3)&3)
  const int srow  = lane >> 2;
  const int schk8 = ((lane & 3) ^ ((lane >> 3) & 3)) * 8;

  const ushort_t* gA[2];
  int aoff[2];
  #pragma unroll
  for (int h = 0; h < 2; h++) {
    int r  = row0 + h * 64 + wid * 16 + srow;
    int rg = m_base + min(r, m_cnt - 1);     // clamp; OOB rows discarded in epilogue
    gA[h]   = A + (size_t)rg * K + kbeg + schk8;
    aoff[h] = (h * 64 + wid * 16) * 32;
  }
  const ushort_t* gB[2] = {nullptr, nullptr};
  const float* Bf = nullptr;
  if constexpr (BPATH == 0) {
    const ushort_t* Bt = (const ushort_t*)Bv + (EXPERT ? (size_t)e * N * K : 0);
    #pragma unroll
    for (int h = 0; h < 2; h++) {
      int n = col0 + h * 64 + wid * 16 + srow;
      gB[h] = Bt + (size_t)n * K + kbeg + schk8;
    }
  } else {
    Bf = (const float*)Bv + (EXPERT ? (size_t)e * (size_t)K * N : 0);
  }
  const int bn  = tid & 127;          // BPATH>=1 staging col
  const int bc0 = (tid >> 7) << 1;    // BPATH>=1 chunk pair

  // --- staging helpers ---
  auto stageA = [&](int pb, int k0) {
    #pragma unroll
    for (int h = 0; h < 2; h++)
      gl2lds16(gA[h] + k0, &As[pb][aoff[h]]);
  };
  auto stageBdma = [&](int pb, int k0) {
    #pragma unroll
    for (int h = 0; h < 2; h++)
      gl2lds16(gB[h] + k0, &Bs[pb][aoff[h]]);
  };
  auto issueB = [&](int k0, float* br) {   // global fp32 -> regs (issue early)
    #pragma unroll
    for (int ci = 0; ci < 2; ci++)
      #pragma unroll
      for (int j = 0; j < 8; j++) {
        int kk = kbeg + k0 + (bc0 + ci) * 8 + j;
        int krow = (BPATH == 2) ? ((kk < 2048) ? (kk & 1023) : (kk - 2048)) : kk;
        br[ci * 8 + j] = Bf[(size_t)krow * N + col0 + bn];
      }
  };
  auto writeB = [&](int pb, int k0, const float* br) {  // convert + ds_write (late)
    #pragma unroll
    for (int ci = 0; ci < 2; ci++) {
      int c = bc0 + ci;
      bool lo = (BPATH == 2) && ((kbeg + k0 + c * 8) >= 2048);
      union { ushort_t u[8]; uint4 v; } pk;
      #pragma unroll
      for (int j = 0; j < 8; j++) {
        float xv = br[ci * 8 + j];
        ushort_t hv = f2bf(xv);
        pk.u[j] = lo ? f2bf(xv - bf2f(hv)) : hv;
      }
      int s = c ^ ((bn >> 1) & 3);
      *(uint4*)(&Bs[pb][bn * 32 + s * 8]) = pk.v;
    }
  };

  f32x4 acc[4][4];
  #pragma unroll
  for (int i = 0; i < 4; i++)
    #pragma unroll
    for (int j = 0; j < 4; j++)
      acc[i][j] = (f32x4){0.f, 0.f, 0.f, 0.f};

  // fragment read constants
  const int q  = lane >> 4;
  const int rr = lane & 15;
  const int sw8 = (q ^ ((rr >> 1) & 3)) * 8;
  const int abase = (wm * 64 + rr) * 32 + sw8;
  const int bbase = (wn * 64 + rr) * 32 + sw8;

  const int nkt = Kc >> 5;

  // prologue: stage tile 0 into buffer 0
  stageA(0, 0);
  if constexpr (BPATH == 0) {
    stageBdma(0, 0);
  } else {
    float br0[16];
    issueB(0, br0);
    writeB(0, 0, br0);
  }
  __syncthreads();   // drains vmcnt(0)+lgkmcnt(0): tile 0 resident

  for (int kt = 0; kt < nkt; kt++) {
    const int cur = kt & 1, nxt = cur ^ 1;
    const int k0n = (kt + 1) << 5;
    const bool hn = (kt + 1 < nkt);
    float breg[16];
    if (hn) {
      stageA(nxt, k0n);                       // DMA, no VGPR dest
      if constexpr (BPATH == 0) stageBdma(nxt, k0n);
      else issueB(k0n, breg);                 // loads in flight across MFMAs
    }

    short8 af[4], bfr[4];
    #pragma unroll
    for (int i = 0; i < 4; i++) {
      af[i]  = *(const short8*)(&As[cur][abase + i * 512]);
      bfr[i] = *(const short8*)(&Bs[cur][bbase + i * 512]);
    }
    #pragma unroll
    for (int mt = 0; mt < 4; mt++)
      #pragma unroll
      for (int nt = 0; nt < 4; nt++)
        acc[mt][nt] = __builtin_amdgcn_mfma_f32_16x16x32_bf16(af[mt], bfr[nt], acc[mt][nt], 0, 0, 0);

    if (hn && BPATH >= 1) writeB(nxt, k0n, breg);
    __syncthreads();  // waits lgkmcnt(0) (reads of cur done) + vmcnt(0) (nxt DMA done)
  }

  // epilogue. C/D layout: col=lane&15, row=(lane>>4)*4+i  (m89-verified)
  const float* biasp = bias + (EXPERT ? (size_t)e * N : 0);
  float bv[4];
  #pragma unroll
  for (int nt = 0; nt < 4; nt++)
    bv[nt] = biasp[col0 + wn * 64 + nt * 16 + rr];
  const float bscale = (SPLITK == 1 || kc == 0) ? 1.f : 0.f;

  #pragma unroll
  for (int mt = 0; mt < 4; mt++) {
    #pragma unroll
    for (int i = 0; i < 4; i++) {
      int r_loc = row0 + wm * 64 + mt * 16 + q * 4 + i;
      if (r_loc < m_cnt) {
        int slot = m_base + r_loc;
        float g = 1.f;
        if (OUTMODE == 3) g = slot_gate[slot];
        #pragma unroll
        for (int nt = 0; nt < 4; nt++) {
          float v = acc[mt][nt][i] + bscale * bv[nt];
          if (RELU) v = fmaxf(v, 0.f);
          int c = col0 + wn * 64 + nt * 16 + rr;
          if (OUTMODE == 0)      ((float*)Cout)[(size_t)slot * N + c]    = v;
          else if (OUTMODE == 1) ((ushort_t*)Cout)[(size_t)slot * N + c] = f2bf(v);
          else ((float*)Cout)[((size_t)kc * SLOTS + slot) * N + c] = g * v;
        }
      }
    }
  }
}

// score = h @ rw2 + rb2 (fp32), then top-2 + softmax gates + expert counts.
__global__ void router_score(const float* __restrict__ h, const float* __restrict__ rw2,
                             const float* __restrict__ rb2, int* __restrict__ topi,
                             float* __restrict__ gates, int* __restrict__ counts)
{
  int t = blockIdx.x * 4 + (threadIdx.x >> 6);
  if (t >= TOKENS) return;
  int lane = threadIdx.x & 63;
  const float* hr = h + (size_t)t * DFF;
  float acc[8] = {0,0,0,0,0,0,0,0};
  for (int j = lane; j < DFF; j += 64) {
    float hv = hr[j];
    const float4* w = (const float4*)(rw2 + (size_t)j * 8);
    float4 w0 = w[0], w1 = w[1];
    acc[0] += hv * w0.x; acc[1] += hv * w0.y; acc[2] += hv * w0.z; acc[3] += hv * w0.w;
    acc[4] += hv * w1.x; acc[5] += hv * w1.y; acc[6] += hv * w1.z; acc[7] += hv * w1.w;
  }
  #pragma unroll
  for (int e = 0; e < 8; e++)
    for (int o = 32; o > 0; o >>= 1)
      acc[e] += __shfl_down(acc[e], o);
  if (lane == 0) {
    float s[8];
    #pragma unroll
    for (int e = 0; e < 8; e++) s[e] = acc[e] + rb2[e];
    int i0 = 0;
    #pragma unroll
    for (int e = 1; e < 8; e++) if (s[e] > s[i0]) i0 = e;   // ties -> lower idx (jax)
    int i1 = (i0 == 0) ? 1 : 0;
    #pragma unroll
    for (int e = 0; e < 8; e++) if (e != i0 && s[e] > s[i1]) i1 = e;
    float ex = __expf(s[i1] - s[i0]);
    float g0 = 1.f / (1.f + ex);
    float g1 = ex / (1.f + ex);
    topi[t * 2] = i0; topi[t * 2 + 1] = i1;
    gates[t * 2] = g0; gates[t * 2 + 1] = g1;
    atomicAdd(&counts[i0], 1);
    atomicAdd(&counts[i1], 1);
  }
}

// offsets + compacted live-tile list (tile index -> (expert, y-block))
__global__ void prefix_off(const int* __restrict__ counts, int* __restrict__ off,
                           int* __restrict__ tile_e, int* __restrict__ tile_y)
{
  if (threadIdx.x == 0) {
    int a = 0, t = 0;
    for (int e = 0; e < NEXP; e++) {
      off[e] = a;
      int c = counts[e]; a += c;
      int ty = (c + 127) >> 7;
      for (int y = 0; y < ty; y++) { tile_e[t] = e; tile_y[t] = y; t++; }
    }
    off[NEXP] = a;
    for (; t < TMAX; t++) { tile_e[t] = -1; tile_y[t] = 0; }
  }
}

__global__ void assign_slots(const int* __restrict__ topi, const float* __restrict__ gates,
                             const int* __restrict__ off, int* __restrict__ cursors,
                             int* __restrict__ slot_token, float* __restrict__ slot_gate,
                             int* __restrict__ tok_slot)
{
  int t = blockIdx.x * blockDim.x + threadIdx.x;
  if (t >= TOKENS) return;
  #pragma unroll
  for (int k = 0; k < 2; k++) {
    int e = topi[t * 2 + k];
    int p = atomicAdd(&cursors[e], 1);
    int s = off[e] + p;
    slot_token[s] = t;
    slot_gate[s]  = gates[t * 2 + k];
    tok_slot[t * 2 + k] = s;
  }
}

__global__ void gather_x(const float* __restrict__ x, const int* __restrict__ slot_token,
                         ushort_t* __restrict__ Xg)
{
  int s = blockIdx.x;
  int t = slot_token[s];
  int d = threadIdx.x * 4;
  float4 v = *(const float4*)(x + (size_t)t * EMBED + d);
  ushort4 o;
  o.x = f2bf(v.x); o.y = f2bf(v.y); o.z = f2bf(v.z); o.w = f2bf(v.w);
  *(ushort4*)(Xg + (size_t)s * EMBED + d) = o;
}

// out[t] = sum over {2 slots} x {2 k-chunks} of gated partials (gate/bias folded)
__global__ void combine_out(const float* __restrict__ Ys, const int* __restrict__ tok_slot,
                            float* __restrict__ out)
{
  int t = blockIdx.x;
  int d = threadIdx.x * 4;
  int s0 = tok_slot[t * 2], s1 = tok_slot[t * 2 + 1];
  float4 a = *(const float4*)(Ys + (size_t)s0 * EMBED + d);
  float4 b = *(const float4*)(Ys + ((size_t)SLOTS + s0) * EMBED + d);
  float4 c = *(const float4*)(Ys + (size_t)s1 * EMBED + d);
  float4 e = *(const float4*)(Ys + ((size_t)SLOTS + s1) * EMBED + d);
  float4 o;
  o.x = (a.x + b.x) + (c.x + e.x);
  o.y = (a.y + b.y) + (c.y + e.y);
  o.z = (a.z + b.z) + (c.z + e.z);
  o.w = (a.w + b.w) + (c.w + e.w);
  *(float4*)(out + (size_t)t * EMBED + d) = o;
}

extern "C" void kernel_launch(void* const* d_in, const int* in_sizes, int n_in,
                              void* d_out, int out_size, void* d_ws, size_t ws_size,
                              hipStream_t stream)
{
  const float* x   = (const float*)d_in[0];
  const float* rw1 = (const float*)d_in[1];
  const float* rb1 = (const float*)d_in[2];
  const float* rw2 = (const float*)d_in[3];
  const float* rb2 = (const float*)d_in[4];
  const float* W1  = (const float*)d_in[5];
  const float* b1  = (const float*)d_in[6];
  const float* W2  = (const float*)d_in[7];
  const float* b2  = (const float*)d_in[8];
  float* out = (float*)d_out;
  char* ws = (char*)d_ws;

  // Layout unchanged from R5 (RW1t region now unused but keeps aliasing simple):
  // [ (RW1t dead) 25.2MB][Xs3 12.6MB][Xg 8.4MB][Hs/h 33.5MB][small]
  // Ys [2][4096][1024] f32 (33.5MB) aliases head region (dead after router GEMM).
  const size_t SZ_RW1T = (size_t)4096 * 3072 * 2;
  const size_t SZ_XS3  = (size_t)2048 * 3072 * 2;
  const size_t SZ_XG   = (size_t)SLOTS * EMBED * 2;
  const size_t SZ_H    = (size_t)SLOTS * DFF * 2;

  float*    Ys   = (float*)ws;                         // [2*SLOTS, 1024] f32
  ushort_t* Xs3  = (ushort_t*)(ws + SZ_RW1T);
  ushort_t* Xg   = (ushort_t*)(ws + SZ_RW1T + SZ_XS3);
  ushort_t* Hs   = (ushort_t*)(ws + SZ_RW1T + SZ_XS3 + SZ_XG);
  float*    h    = (float*)Hs;                         // h aliases Hs (disjoint lifetimes)
  char* ps = ws + SZ_RW1T + SZ_XS3 + SZ_XG + SZ_H;
  int*   topi       = (int*)ps;    ps += TOKENS * 2 * 4;
  float* gates      = (float*)ps;  ps += TOKENS * 2 * 4;
  int*   tok_slot   = (int*)ps;    ps += TOKENS * 2 * 4;
  int*   slot_token = (int*)ps;    ps += SLOTS * 4;
  float* slot_gate  = (float*)ps;  ps += SLOTS * 4;
  int*   counts     = (int*)ps;    ps += 256;
  int*   cursors    = (int*)ps;    ps += 256;
  int*   off        = (int*)ps;    ps += 256;
  int*   tile_e     = (int*)ps;    ps += 256;
  int*   tile_y     = (int*)ps;    ps += 256;

  zero_small<<<1, 64, 0, stream>>>(counts, cursors);
  split_x3<<<TOKENS, 256, 0, stream>>>(x, Xs3);

  // Router: h = relu(Xs3 @ split(rw1)^T + rb1), fp32, K'=3072, rw1 staged in-kernel
  gemm_kernel<2, 0, true, false, 1, 32>
      <<<dim3(32, 16, 1), 256, 0, stream>>>(Xs3, rw1, rb1, h, nullptr,
                                            nullptr, nullptr, nullptr, TOKENS, DFF, 3072);
  router_score<<<512, 256, 0, stream>>>(h, rw2, rb2, topi, gates, counts);
  prefix_off  <<<1, 64, 0, stream>>>(counts, off, tile_e, tile_y);
  assign_slots<<<8, 256, 0, stream>>>(topi, gates, off, cursors, slot_token, slot_gate, tok_slot);
  gather_x    <<<SLOTS, 256, 0, stream>>>(x, slot_token, Xg);

  // Expert GEMM1: Hs = relu(Xg @ W1[e] + b1[e]), bf16 out; W1 staged fp32->bf16 in-kernel
  gemm_kernel<1, 1, true, true, 1, 32>
      <<<dim3(32 * TMAX, 1, 1), 256, 0, stream>>>(Xg, W1, b1, Hs,
          nullptr, off, tile_e, tile_y, 0, DFF, EMBED);
  // Expert GEMM2: Ys[kc][slot] = gate*(Hs @ W2[e] kc-chunk + [kc==0]*b2[e]), fp32 partials
  gemm_kernel<1, 3, false, true, 2, 8>
      <<<dim3(8 * 2 * TMAX, 1, 1), 256, 0, stream>>>(Hs, W2, b2, Ys,
          slot_gate, off, tile_e, tile_y, 0, EMBED, DFF);

  combine_out<<<TOKENS, 256, 0, stream>>>(Ys, tok_slot, out);
}

// Round 2
// 646.068 us; speedup vs baseline: 1.0306x; 1.0306x over previous
//
#include <hip/hip_runtime.h>
#include <stdint.h>

// SparseMoE gfx950, Round 7.
// R6 post-mortem: prefetch + in-GEMM fp32->bf16 B staging spilled (VGPR=64,
// VALUBusy 57%, 146us/GEMM). Conversion work cannot live across the MFMA block.
// R7: per-k-step B work -> ZERO VALU. All weights pre-transposed/converted to
// bf16 [n][k] via transp_conv (proven R5 code), all 3 GEMMs run pure-DMA
// double-buffered prefetch (T3-minimum 2-phase: stage(nxt) -> ds_read+MFMA ->
// one vmcnt(0)+barrier per k-step).
// ws discipline (proven >=109MB only): weights converted in 4-expert HALVES
// into one 33.5MB region, interleaved with half-GEMM launches.
//  - Xg deleted: GEMM1 gathers A rows via slot_token in DMA addressing.
//  - Xs3 [xh|xl|xh] -> Xhl [xh|xl]; router's 3rd k-segment folded by address
//    map (2048-boundary is 32-aligned -> wave-uniform fold per k-step).
// Regions: A[33.5] = RW1t then W1t/W2t halves; B[33.5] = h then Hs;
//          C[33.5] = Xhl then Ys. Peak ~101MB.
typedef unsigned short ushort_t;
typedef __attribute__((ext_vector_type(8))) short short8;
typedef __attribute__((ext_vector_type(4))) float f32x4;

#define EMBED   1024
#define DFF     4096
#define NEXP    8
#define TOKENS  2048
#define SLOTS   4096
#define TMAX    40    // >= max Sum_e ceil(cnt_e/128) = 32+7 = 39

__device__ __forceinline__ ushort_t f2bf(float f) {
  unsigned u = __float_as_uint(f);
  u += 0x7FFFu + ((u >> 16) & 1u);   // RNE
  return (ushort_t)(u >> 16);
}
__device__ __forceinline__ float bf2f(ushort_t b) {
  return __uint_as_float(((unsigned)b) << 16);
}

// async 16B/lane global->LDS DMA. LDS dest wave-uniform; lane i lands at +16*i.
__device__ __forceinline__ void gl2lds16(const void* g, void* l) {
  typedef const __attribute__((address_space(1))) unsigned char* gp_t;
  typedef __attribute__((address_space(3))) unsigned char* lp_t;
  __builtin_amdgcn_global_load_lds((gp_t)(uintptr_t)g, (lp_t)(uintptr_t)l, 16, 0, 0);
}

__global__ void zero_small(int* counts, int* cursors) {
  int i = threadIdx.x;
  if (i < NEXP) { counts[i] = 0; cursors[i] = 0; }
}

// x [2048,1024] f32 -> Xhl [2048,2048] bf16 : [xh | xl]
__global__ void split_xhl(const float* __restrict__ x, ushort_t* __restrict__ Xs) {
  int t = blockIdx.x;
  int d = threadIdx.x * 4;
  float4 v = *(const float4*)(x + (size_t)t * EMBED + d);
  ushort4 hi, lo;
  hi.x = f2bf(v.x); lo.x = f2bf(v.x - bf2f(hi.x));
  hi.y = f2bf(v.y); lo.y = f2bf(v.y - bf2f(hi.y));
  hi.z = f2bf(v.z); lo.z = f2bf(v.z - bf2f(hi.z));
  hi.w = f2bf(v.w); lo.w = f2bf(v.w - bf2f(hi.w));
  ushort_t* row = Xs + (size_t)t * 2048;
  *(ushort4*)(row + d)        = hi;
  *(ushort4*)(row + 1024 + d) = lo;
}

// transpose+convert: dst[n][dst_koff+k] = bf16( src[k][n] )  (lo: bf16 residual)
__global__ void transp_conv(const float* __restrict__ src, ushort_t* __restrict__ dst,
                            int src_ld, int dst_ld, long src_estride, long dst_estride,
                            int dst_koff, int lo)
{
  __shared__ float t[64][65];
  const float* s = src + (size_t)blockIdx.z * src_estride;
  ushort_t* d = dst + (size_t)blockIdx.z * dst_estride;
  int n0 = blockIdx.x * 64, k0 = blockIdx.y * 64;
  int tid = threadIdx.x;
  int kk = tid >> 4, nn = (tid & 15) * 4;
  #pragma unroll
  for (int it = 0; it < 4; it++) {
    float4 v = *(const float4*)(s + (size_t)(k0 + kk + it * 16) * src_ld + n0 + nn);
    t[kk + it * 16][nn]     = v.x;
    t[kk + it * 16][nn + 1] = v.y;
    t[kk + it * 16][nn + 2] = v.z;
    t[kk + it * 16][nn + 3] = v.w;
  }
  __syncthreads();
  int nn2 = tid >> 3, kk2 = (tid & 7) * 8;
  #pragma unroll
  for (int it = 0; it < 2; it++) {
    int n = nn2 + it * 32;
    union { ushort_t u[8]; uint4 v; } pk;
    #pragma unroll
    for (int j = 0; j < 8; j++) {
      float xv = t[kk2 + j][n];
      ushort_t hv = f2bf(xv);
      pk.u[j] = lo ? f2bf(xv - bf2f(hv)) : hv;
    }
    *(uint4*)(d + (size_t)(n0 + n) * dst_ld + dst_koff + k0 + kk2) = pk.v;
  }
}

// ---------------- MFMA GEMM (pure-DMA prefetch) ----------------
// 128x128 tile, BK=32, 4 waves 2x2, 4x4 mfma_16x16x32_bf16.
// Double-buffered LDS, chunk-XOR swizzle slot(q,row)=q^((row>>1)&3).
// One barrier per k-step; tile t+1 DMA issued before tile t's ds_read+MFMA.
// A and B are both bf16; B layout [n][K] (pre-transposed).
// APATH 0: direct rows, row stride K (A indexed by m_base+slot).
//       1: router Xhl, row stride 2048; k>=2048 folds to k-2048 (xh reuse).
//       2: gather rows via slot_token, row stride 2048, cols 0..K-1 = xh.
// EXPERT: 1-D grid, bid = xi + NX*(kc + SPLITK*t); tiles outside [e0,e1) exit.
// OUTMODE 0: f32 store [slot][c]. 1: bf16 store [slot][c].
//         3: f32 gated partial store [kc][slot][c] (bias folded on kc==0).
template<int APATH, int OUTMODE, bool RELU, bool EXPERT, int SPLITK, int NX>
__global__ __launch_bounds__(256, 3)
void gemm_kernel(const ushort_t* __restrict__ A, const ushort_t* __restrict__ B,
                 const float* __restrict__ bias, void* __restrict__ Cout,
                 const float* __restrict__ slot_gate, const int* __restrict__ slot_token,
                 const int* __restrict__ off, const int* __restrict__ tile_e,
                 const int* __restrict__ tile_y, int e0, int e1,
                 int M, int N, int K)
{
  __shared__ ushort_t As[2][128 * 32];
  __shared__ ushort_t Bs[2][128 * 32];

  int e = 0, kc = 0, row0, col0, m_base, m_cnt;
  if (EXPERT) {
    int bid  = blockIdx.x;
    int xi   = bid % NX;
    int rest = bid / NX;
    kc       = rest % SPLITK;
    int t    = rest / SPLITK;
    e = tile_e[t];
    if (e < e0 || e >= e1) return;        // padded tail / other half, uniform exit
    row0   = tile_y[t] * 128;
    col0   = xi * 128;
    m_base = off[e];
    m_cnt  = off[e + 1] - m_base;
  } else {
    row0 = blockIdx.y * 128;
    col0 = blockIdx.x * 128;
    m_base = 0; m_cnt = M;
    if (row0 >= m_cnt) return;
  }
  const int Kc   = K / SPLITK;
  const int kbeg = kc * Kc;

  const int tid  = threadIdx.x;
  const int lane = tid & 63;
  const int wid  = tid >> 6;
  const int wm = wid & 1, wn = wid >> 1;

  // staging lane constants (DMA): lane i -> tile row base+(i>>2), slot i&3,
  // fetched global chunk = (i&3) ^ ((i>>3)&3)
  const int srow  = lane >> 2;
  const int schk8 = ((lane & 3) ^ ((lane >> 3) & 3)) * 8;

  const ushort_t* gA[2];
  const ushort_t* gB[2];
  int aoff[2];
  const ushort_t* Bt = B + (EXPERT ? (size_t)(e - e0) * (size_t)N * K : 0);
  #pragma unroll
  for (int h = 0; h < 2; h++) {
    int r  = row0 + h * 64 + wid * 16 + srow;
    int rl = min(r, m_cnt - 1);              // clamp; OOB rows discarded in epilogue
    size_t rowb;
    if (APATH == 2)      rowb = (size_t)slot_token[m_base + rl] * 2048;
    else if (APATH == 1) rowb = (size_t)rl * 2048;
    else                 rowb = (size_t)(m_base + rl) * (size_t)K;
    gA[h]   = A + rowb + (APATH == 0 ? kbeg : 0) + schk8;
    aoff[h] = (h * 64 + wid * 16) * 32;

    int n = col0 + h * 64 + wid * 16 + srow;
    gB[h] = Bt + (size_t)n * K + kbeg + schk8;
  }

  auto stage = [&](int pb, int k0) {
    // router fold: k' in [2048,3072) reads xh cols k'-2048 (boundary 32-aligned,
    // k0 wave-uniform -> uniform select, never straddles within a chunk)
    const int k0a = (APATH == 1 && k0 >= 2048) ? k0 - 2048 : k0;
    #pragma unroll
    for (int h = 0; h < 2; h++) {
      gl2lds16(gA[h] + k0a, &As[pb][aoff[h]]);
      gl2lds16(gB[h] + k0,  &Bs[pb][aoff[h]]);
    }
  };

  f32x4 acc[4][4];
  #pragma unroll
  for (int i = 0; i < 4; i++)
    #pragma unroll
    for (int j = 0; j < 4; j++)
      acc[i][j] = (f32x4){0.f, 0.f, 0.f, 0.f};

  // fragment read constants
  const int q  = lane >> 4;
  const int rr = lane & 15;
  const int sw8 = (q ^ ((rr >> 1) & 3)) * 8;
  const int abase = (wm * 64 + rr) * 32 + sw8;
  const int bbase = (wn * 64 + rr) * 32 + sw8;

  const int nkt = Kc >> 5;

  stage(0, 0);
  __syncthreads();   // drains vmcnt(0): tile 0 resident

  for (int kt = 0; kt < nkt; kt++) {
    const int cur = kt & 1, nxt = cur ^ 1;
    if (kt + 1 < nkt) stage(nxt, (kt + 1) << 5);   // in flight across MFMAs

    short8 af[4], bfr[4];
    #pragma unroll
    for (int i = 0; i < 4; i++) {
      af[i]  = *(const short8*)(&As[cur][abase + i * 512]);
      bfr[i] = *(const short8*)(&Bs[cur][bbase + i * 512]);
    }
    #pragma unroll
    for (int mt = 0; mt < 4; mt++)
      #pragma unroll
      for (int nt = 0; nt < 4; nt++)
        acc[mt][nt] = __builtin_amdgcn_mfma_f32_16x16x32_bf16(af[mt], bfr[nt], acc[mt][nt], 0, 0, 0);

    __syncthreads();  // lgkmcnt(0): cur reads done; vmcnt(0): nxt DMA landed
  }

  // epilogue. C/D layout: col=lane&15, row=(lane>>4)*4+i  (m89-verified)
  const float* biasp = bias + (EXPERT ? (size_t)e * N : 0);
  float bv[4];
  #pragma unroll
  for (int nt = 0; nt < 4; nt++)
    bv[nt] = biasp[col0 + wn * 64 + nt * 16 + rr];
  const float bscale = (SPLITK == 1 || kc == 0) ? 1.f : 0.f;

  #pragma unroll
  for (int mt = 0; mt < 4; mt++) {
    #pragma unroll
    for (int i = 0; i < 4; i++) {
      int r_loc = row0 + wm * 64 + mt * 16 + q * 4 + i;
      if (r_loc < m_cnt) {
        int slot = m_base + r_loc;
        float g = 1.f;
        if (OUTMODE == 3) g = slot_gate[slot];
        #pragma unroll
        for (int nt = 0; nt < 4; nt++) {
          float v = acc[mt][nt][i] + bscale * bv[nt];
          if (RELU) v = fmaxf(v, 0.f);
          int c = col0 + wn * 64 + nt * 16 + rr;
          if (OUTMODE == 0)      ((float*)Cout)[(size_t)slot * N + c]    = v;
          else if (OUTMODE == 1) ((ushort_t*)Cout)[(size_t)slot * N + c] = f2bf(v);
          else ((float*)Cout)[((size_t)kc * SLOTS + slot) * N + c] = g * v;
        }
      }
    }
  }
}

// score = h @ rw2 + rb2 (fp32), then top-2 + softmax gates + expert counts.
__global__ void router_score(const float* __restrict__ h, const float* __restrict__ rw2,
                             const float* __restrict__ rb2, int* __restrict__ topi,
                             float* __restrict__ gates, int* __restrict__ counts)
{
  int t = blockIdx.x * 4 + (threadIdx.x >> 6);
  if (t >= TOKENS) return;
  int lane = threadIdx.x & 63;
  const float* hr = h + (size_t)t * DFF;
  float acc[8] = {0,0,0,0,0,0,0,0};
  for (int j = lane; j < DFF; j += 64) {
    float hv = hr[j];
    const float4* w = (const float4*)(rw2 + (size_t)j * 8);
    float4 w0 = w[0], w1 = w[1];
    acc[0] += hv * w0.x; acc[1] += hv * w0.y; acc[2] += hv * w0.z; acc[3] += hv * w0.w;
    acc[4] += hv * w1.x; acc[5] += hv * w1.y; acc[6] += hv * w1.z; acc[7] += hv * w1.w;
  }
  #pragma unroll
  for (int e = 0; e < 8; e++)
    for (int o = 32; o > 0; o >>= 1)
      acc[e] += __shfl_down(acc[e], o);
  if (lane == 0) {
    float s[8];
    #pragma unroll
    for (int e = 0; e < 8; e++) s[e] = acc[e] + rb2[e];
    int i0 = 0;
    #pragma unroll
    for (int e = 1; e < 8; e++) if (s[e] > s[i0]) i0 = e;   // ties -> lower idx (jax)
    int i1 = (i0 == 0) ? 1 : 0;
    #pragma unroll
    for (int e = 0; e < 8; e++) if (e != i0 && s[e] > s[i1]) i1 = e;
    float ex = __expf(s[i1] - s[i0]);
    float g0 = 1.f / (1.f + ex);
    float g1 = ex / (1.f + ex);
    topi[t * 2] = i0; topi[t * 2 + 1] = i1;
    gates[t * 2] = g0; gates[t * 2 + 1] = g1;
    atomicAdd(&counts[i0], 1);
    atomicAdd(&counts[i1], 1);
  }
}

// offsets + compacted live-tile list (tile index -> (expert, y-block))
__global__ void prefix_off(const int* __restrict__ counts, int* __restrict__ off,
                           int* __restrict__ tile_e, int* __restrict__ tile_y)
{
  if (threadIdx.x == 0) {
    int a = 0, t = 0;
    for (int e = 0; e < NEXP; e++) {
      off[e] = a;
      int c = counts[e]; a += c;
      int ty = (c + 127) >> 7;
      for (int y = 0; y < ty; y++) { tile_e[t] = e; tile_y[t] = y; t++; }
    }
    off[NEXP] = a;
    for (; t < TMAX; t++) { tile_e[t] = -1; tile_y[t] = 0; }
  }
}

__global__ void assign_slots(const int* __restrict__ topi, const float* __restrict__ gates,
                             const int* __restrict__ off, int* __restrict__ cursors,
                             int* __restrict__ slot_token, float* __restrict__ slot_gate,
                             int* __restrict__ tok_slot)
{
  int t = blockIdx.x * blockDim.x + threadIdx.x;
  if (t >= TOKENS) return;
  #pragma unroll
  for (int k = 0; k < 2; k++) {
    int e = topi[t * 2 + k];
    int p = atomicAdd(&cursors[e], 1);
    int s = off[e] + p;
    slot_token[s] = t;
    slot_gate[s]  = gates[t * 2 + k];
    tok_slot[t * 2 + k] = s;
  }
}

// out[t] = sum over {2 slots} x {2 k-chunks} of gated partials (gate/bias folded)
__global__ void combine_out(const float* __restrict__ Ys, const int* __restrict__ tok_slot,
                            float* __restrict__ out)
{
  int t = blockIdx.x;
  int d = threadIdx.x * 4;
  int s0 = tok_slot[t * 2], s1 = tok_slot[t * 2 + 1];
  float4 a = *(const float4*)(Ys + (size_t)s0 * EMBED + d);
  float4 b = *(const float4*)(Ys + ((size_t)SLOTS + s0) * EMBED + d);
  float4 c = *(const float4*)(Ys + (size_t)s1 * EMBED + d);
  float4 e = *(const float4*)(Ys + ((size_t)SLOTS + s1) * EMBED + d);
  float4 o;
  o.x = (a.x + b.x) + (c.x + e.x);
  o.y = (a.y + b.y) + (c.y + e.y);
  o.z = (a.z + b.z) + (c.z + e.z);
  o.w = (a.w + b.w) + (c.w + e.w);
  *(float4*)(out + (size_t)t * EMBED + d) = o;
}

extern "C" void kernel_launch(void* const* d_in, const int* in_sizes, int n_in,
                              void* d_out, int out_size, void* d_ws, size_t ws_size,
                              hipStream_t stream)
{
  const float* x   = (const float*)d_in[0];
  const float* rw1 = (const float*)d_in[1];
  const float* rb1 = (const float*)d_in[2];
  const float* rw2 = (const float*)d_in[3];
  const float* rb2 = (const float*)d_in[4];
  const float* W1  = (const float*)d_in[5];
  const float* b1  = (const float*)d_in[6];
  const float* W2  = (const float*)d_in[7];
  const float* b2  = (const float*)d_in[8];
  float* out = (float*)d_out;
  char* ws = (char*)d_ws;

  // Regions (all 33.5 MB), disjoint lifetimes within each:
  // A: RW1t [4096][3072] bf16 (router) -> WT = 4-expert W1t/W2t halves [n][k] bf16
  // B: h [2048][4096] f32 (router out) -> Hs [4096][4096] bf16 (GEMM1 out)
  // C: Xhl [2048][2048] bf16           -> Ys [2][4096][1024] f32 (GEMM2 partials)
  const size_t SZ_R = (size_t)4096 * 4096 * 2;   // 33.5 MB

  ushort_t* RW1t = (ushort_t*)ws;                 // region A
  ushort_t* WT   = (ushort_t*)ws;
  float*    h    = (float*)(ws + SZ_R);           // region B
  ushort_t* Hs   = (ushort_t*)(ws + SZ_R);
  ushort_t* Xhl  = (ushort_t*)(ws + 2 * SZ_R);    // region C
  float*    Ys   = (float*)(ws + 2 * SZ_R);
  char* ps = ws + 3 * SZ_R;
  int*   topi       = (int*)ps;    ps += TOKENS * 2 * 4;
  float* gates      = (float*)ps;  ps += TOKENS * 2 * 4;
  int*   tok_slot   = (int*)ps;    ps += TOKENS * 2 * 4;
  int*   slot_token = (int*)ps;    ps += SLOTS * 4;
  float* slot_gate  = (float*)ps;  ps += SLOTS * 4;
  int*   counts     = (int*)ps;    ps += 256;
  int*   cursors    = (int*)ps;    ps += 256;
  int*   off        = (int*)ps;    ps += 256;
  int*   tile_e     = (int*)ps;    ps += 256;
  int*   tile_y     = (int*)ps;    ps += 256;

  zero_small<<<1, 64, 0, stream>>>(counts, cursors);
  split_xhl<<<TOKENS, 256, 0, stream>>>(x, Xhl);

  // RW1t [n=4096][k'=3072] = [wh | wh | wl] transposed from rw1 [1024][4096]
  transp_conv<<<dim3(64, 16, 1), 256, 0, stream>>>(rw1, RW1t, DFF, 3072, 0, 0, 0,    0);
  transp_conv<<<dim3(64, 16, 1), 256, 0, stream>>>(rw1, RW1t, DFF, 3072, 0, 0, 1024, 0);
  transp_conv<<<dim3(64, 16, 1), 256, 0, stream>>>(rw1, RW1t, DFF, 3072, 0, 0, 2048, 1);

  // Router: h = relu(Xhl @ RW1t^T + rb1), fp32, K'=3072 (A k>=2048 folds to xh)
  gemm_kernel<1, 0, true, false, 1, 32>
      <<<dim3(32, 16, 1), 256, 0, stream>>>(Xhl, RW1t, rb1, h, nullptr, nullptr,
                                            nullptr, nullptr, nullptr, 0, NEXP,
                                            TOKENS, DFF, 3072);
  router_score<<<512, 256, 0, stream>>>(h, rw2, rb2, topi, gates, counts);
  prefix_off  <<<1, 64, 0, stream>>>(counts, off, tile_e, tile_y);
  assign_slots<<<8, 256, 0, stream>>>(topi, gates, off, cursors, slot_token, slot_gate, tok_slot);

  const long W1ES = (long)EMBED * DFF;   // floats per expert
  const long W2ES = (long)DFF * EMBED;

  for (int half = 0; half < 2; half++) {
    int e0 = half * 4;
    // WT <- bf16 W1[e0..e0+3]^T  : [k=1024][n=4096] -> [n=4096][k=1024]
    transp_conv<<<dim3(64, 16, 4), 256, 0, stream>>>(W1 + (size_t)e0 * W1ES, WT,
        DFF, EMBED, W1ES, W1ES, 0, 0);
    // GEMM1: Hs[slot] = relu(xh[token(slot)] @ W1[e] + b1[e]), bf16 out
    gemm_kernel<2, 1, true, true, 1, 32>
        <<<dim3(32 * TMAX, 1, 1), 256, 0, stream>>>(Xhl, WT, b1, Hs,
            nullptr, slot_token, off, tile_e, tile_y, e0, e0 + 4, 0, DFF, EMBED);
  }
  for (int half = 0; half < 2; half++) {
    int e0 = half * 4;
    // WT <- bf16 W2[e0..e0+3]^T  : [k=4096][n=1024] -> [n=1024][k=4096]
    transp_conv<<<dim3(16, 64, 4), 256, 0, stream>>>(W2 + (size_t)e0 * W2ES, WT,
        EMBED, DFF, W2ES, W2ES, 0, 0);
    // GEMM2: Ys[kc][slot] = gate*(Hs @ W2[e] kc-chunk + [kc==0]*b2[e]), f32 partials
    gemm_kernel<0, 3, false, true, 2, 8>
        <<<dim3(8 * 2 * TMAX, 1, 1), 256, 0, stream>>>(Hs, WT, b2, Ys,
            slot_gate, nullptr, off, tile_e, tile_y, e0, e0 + 4, 0, EMBED, DFF);
  }

  combine_out<<<TOKENS, 256, 0, stream>>>(Ys, tok_slot, out);
}

// Round 3
// 619.653 us; speedup vs baseline: 1.0746x; 1.0426x over previous
//
#include <hip/hip_runtime.h>
#include <stdint.h>

// SparseMoE gfx950, Round 8.
// R7 post-mortem: pure-DMA prefetch GEMMs all dropped below 83us (off top-5);
// new #1 is router_score: 83us, VALUBusy 3%, HBM 2.6%, VGPR=16 -> pure
// latency (serial strided h reads, 2 waves/SIMD). h (33.5MB fp32) exists ONLY
// to feed score = relu(h)@rw2.
// R8: delete h + router_score. Router GEMM epilogue fuses the rw2 contraction:
// per row-instance, 32 FMAs vs preloaded rw2 cols + 16-lane shfl_xor butterfly,
// lane rr==0 stores 8-float partials Ps[t][xi2][8] (xi2 = 64-col chunk, 4MB).
// Tiny router_reduce (1 wave/token, coalesced) sums 64 chunks + bias + top-2.
// Scores stay fp32 end-to-end (only sum order changes vs R7).
typedef unsigned short ushort_t;
typedef __attribute__((ext_vector_type(8))) short short8;
typedef __attribute__((ext_vector_type(4))) float f32x4;

#define EMBED   1024
#define DFF     4096
#define NEXP    8
#define TOKENS  2048
#define SLOTS   4096
#define TMAX    40    // >= max Sum_e ceil(cnt_e/128) = 32+7 = 39

__device__ __forceinline__ ushort_t f2bf(float f) {
  unsigned u = __float_as_uint(f);
  u += 0x7FFFu + ((u >> 16) & 1u);   // RNE
  return (ushort_t)(u >> 16);
}
__device__ __forceinline__ float bf2f(ushort_t b) {
  return __uint_as_float(((unsigned)b) << 16);
}

// async 16B/lane global->LDS DMA. LDS dest wave-uniform; lane i lands at +16*i.
__device__ __forceinline__ void gl2lds16(const void* g, void* l) {
  typedef const __attribute__((address_space(1))) unsigned char* gp_t;
  typedef __attribute__((address_space(3))) unsigned char* lp_t;
  __builtin_amdgcn_global_load_lds((gp_t)(uintptr_t)g, (lp_t)(uintptr_t)l, 16, 0, 0);
}

__global__ void zero_small(int* counts, int* cursors) {
  int i = threadIdx.x;
  if (i < NEXP) { counts[i] = 0; cursors[i] = 0; }
}

// x [2048,1024] f32 -> Xhl [2048,2048] bf16 : [xh | xl]
__global__ void split_xhl(const float* __restrict__ x, ushort_t* __restrict__ Xs) {
  int t = blockIdx.x;
  int d = threadIdx.x * 4;
  float4 v = *(const float4*)(x + (size_t)t * EMBED + d);
  ushort4 hi, lo;
  hi.x = f2bf(v.x); lo.x = f2bf(v.x - bf2f(hi.x));
  hi.y = f2bf(v.y); lo.y = f2bf(v.y - bf2f(hi.y));
  hi.z = f2bf(v.z); lo.z = f2bf(v.z - bf2f(hi.z));
  hi.w = f2bf(v.w); lo.w = f2bf(v.w - bf2f(hi.w));
  ushort_t* row = Xs + (size_t)t * 2048;
  *(ushort4*)(row + d)        = hi;
  *(ushort4*)(row + 1024 + d) = lo;
}

// transpose+convert: dst[n][dst_koff+k] = bf16( src[k][n] )  (lo: bf16 residual)
__global__ void transp_conv(const float* __restrict__ src, ushort_t* __restrict__ dst,
                            int src_ld, int dst_ld, long src_estride, long dst_estride,
                            int dst_koff, int lo)
{
  __shared__ float t[64][65];
  const float* s = src + (size_t)blockIdx.z * src_estride;
  ushort_t* d = dst + (size_t)blockIdx.z * dst_estride;
  int n0 = blockIdx.x * 64, k0 = blockIdx.y * 64;
  int tid = threadIdx.x;
  int kk = tid >> 4, nn = (tid & 15) * 4;
  #pragma unroll
  for (int it = 0; it < 4; it++) {
    float4 v = *(const float4*)(s + (size_t)(k0 + kk + it * 16) * src_ld + n0 + nn);
    t[kk + it * 16][nn]     = v.x;
    t[kk + it * 16][nn + 1] = v.y;
    t[kk + it * 16][nn + 2] = v.z;
    t[kk + it * 16][nn + 3] = v.w;
  }
  __syncthreads();
  int nn2 = tid >> 3, kk2 = (tid & 7) * 8;
  #pragma unroll
  for (int it = 0; it < 2; it++) {
    int n = nn2 + it * 32;
    union { ushort_t u[8]; uint4 v; } pk;
    #pragma unroll
    for (int j = 0; j < 8; j++) {
      float xv = t[kk2 + j][n];
      ushort_t hv = f2bf(xv);
      pk.u[j] = lo ? f2bf(xv - bf2f(hv)) : hv;
    }
    *(uint4*)(d + (size_t)(n0 + n) * dst_ld + dst_koff + k0 + kk2) = pk.v;
  }
}

// ---------------- MFMA GEMM (pure-DMA prefetch) ----------------
// 128x128 tile, BK=32, 4 waves 2x2, 4x4 mfma_16x16x32_bf16.
// Double-buffered LDS, chunk-XOR swizzle slot(q,row)=q^((row>>1)&3).
// One barrier per k-step; tile t+1 DMA issued before tile t's ds_read+MFMA.
// A and B are both bf16; B layout [n][K] (pre-transposed).
// APATH 0: direct rows, row stride K (A indexed by m_base+slot).
//       1: router Xhl, row stride 2048; k>=2048 folds to k-2048 (xh reuse).
//       2: gather rows via slot_token, row stride 2048, cols 0..K-1 = xh.
// EXPERT: 1-D grid, bid = xi + NX*(kc + SPLITK*t); tiles outside [e0,e1) exit.
// OUTMODE 0: f32 store [slot][c]. 1: bf16 store [slot][c].
//         3: f32 gated partial store [kc][slot][c] (bias folded on kc==0).
//         4: fused router-score partials: slot_gate = rw2 [DFF][8];
//            Cout = Ps [2048][64][8] f32; per (row, 64-col chunk) partial of
//            relu(h) @ rw2 via 16-lane butterfly; no h store at all.
template<int APATH, int OUTMODE, bool RELU, bool EXPERT, int SPLITK, int NX>
__global__ __launch_bounds__(256, 3)
void gemm_kernel(const ushort_t* __restrict__ A, const ushort_t* __restrict__ B,
                 const float* __restrict__ bias, void* __restrict__ Cout,
                 const float* __restrict__ slot_gate, const int* __restrict__ slot_token,
                 const int* __restrict__ off, const int* __restrict__ tile_e,
                 const int* __restrict__ tile_y, int e0, int e1,
                 int M, int N, int K)
{
  __shared__ ushort_t As[2][128 * 32];
  __shared__ ushort_t Bs[2][128 * 32];

  int e = 0, kc = 0, row0, col0, m_base, m_cnt;
  if (EXPERT) {
    int bid  = blockIdx.x;
    int xi   = bid % NX;
    int rest = bid / NX;
    kc       = rest % SPLITK;
    int t    = rest / SPLITK;
    e = tile_e[t];
    if (e < e0 || e >= e1) return;        // padded tail / other half, uniform exit
    row0   = tile_y[t] * 128;
    col0   = xi * 128;
    m_base = off[e];
    m_cnt  = off[e + 1] - m_base;
  } else {
    row0 = blockIdx.y * 128;
    col0 = blockIdx.x * 128;
    m_base = 0; m_cnt = M;
    if (row0 >= m_cnt) return;
  }
  const int Kc   = K / SPLITK;
  const int kbeg = kc * Kc;

  const int tid  = threadIdx.x;
  const int lane = tid & 63;
  const int wid  = tid >> 6;
  const int wm = wid & 1, wn = wid >> 1;

  // staging lane constants (DMA): lane i -> tile row base+(i>>2), slot i&3,
  // fetched global chunk = (i&3) ^ ((i>>3)&3)
  const int srow  = lane >> 2;
  const int schk8 = ((lane & 3) ^ ((lane >> 3) & 3)) * 8;

  const ushort_t* gA[2];
  const ushort_t* gB[2];
  int aoff[2];
  const ushort_t* Bt = B + (EXPERT ? (size_t)(e - e0) * (size_t)N * K : 0);
  #pragma unroll
  for (int h = 0; h < 2; h++) {
    int r  = row0 + h * 64 + wid * 16 + srow;
    int rl = min(r, m_cnt - 1);              // clamp; OOB rows discarded in epilogue
    size_t rowb;
    if (APATH == 2)      rowb = (size_t)slot_token[m_base + rl] * 2048;
    else if (APATH == 1) rowb = (size_t)rl * 2048;
    else                 rowb = (size_t)(m_base + rl) * (size_t)K;
    gA[h]   = A + rowb + (APATH == 0 ? kbeg : 0) + schk8;
    aoff[h] = (h * 64 + wid * 16) * 32;

    int n = col0 + h * 64 + wid * 16 + srow;
    gB[h] = Bt + (size_t)n * K + kbeg + schk8;
  }

  auto stage = [&](int pb, int k0) {
    // router fold: k' in [2048,3072) reads xh cols k'-2048 (boundary 32-aligned,
    // k0 wave-uniform -> uniform select, never straddles within a chunk)
    const int k0a = (APATH == 1 && k0 >= 2048) ? k0 - 2048 : k0;
    #pragma unroll
    for (int h = 0; h < 2; h++) {
      gl2lds16(gA[h] + k0a, &As[pb][aoff[h]]);
      gl2lds16(gB[h] + k0,  &Bs[pb][aoff[h]]);
    }
  };

  f32x4 acc[4][4];
  #pragma unroll
  for (int i = 0; i < 4; i++)
    #pragma unroll
    for (int j = 0; j < 4; j++)
      acc[i][j] = (f32x4){0.f, 0.f, 0.f, 0.f};

  // fragment read constants
  const int q  = lane >> 4;
  const int rr = lane & 15;
  const int sw8 = (q ^ ((rr >> 1) & 3)) * 8;
  const int abase = (wm * 64 + rr) * 32 + sw8;
  const int bbase = (wn * 64 + rr) * 32 + sw8;

  const int nkt = Kc >> 5;

  stage(0, 0);
  __syncthreads();   // drains vmcnt(0): tile 0 resident

  for (int kt = 0; kt < nkt; kt++) {
    const int cur = kt & 1, nxt = cur ^ 1;
    if (kt + 1 < nkt) stage(nxt, (kt + 1) << 5);   // in flight across MFMAs

    short8 af[4], bfr[4];
    #pragma unroll
    for (int i = 0; i < 4; i++) {
      af[i]  = *(const short8*)(&As[cur][abase + i * 512]);
      bfr[i] = *(const short8*)(&Bs[cur][bbase + i * 512]);
    }
    #pragma unroll
    for (int mt = 0; mt < 4; mt++)
      #pragma unroll
      for (int nt = 0; nt < 4; nt++)
        acc[mt][nt] = __builtin_amdgcn_mfma_f32_16x16x32_bf16(af[mt], bfr[nt], acc[mt][nt], 0, 0, 0);

    __syncthreads();  // lgkmcnt(0): cur reads done; vmcnt(0): nxt DMA landed
  }

  // epilogue. C/D layout: col=lane&15, row=(lane>>4)*4+i  (m89-verified)
  const float* biasp = bias + (EXPERT ? (size_t)e * N : 0);
  float bv[4];
  #pragma unroll
  for (int nt = 0; nt < 4; nt++)
    bv[nt] = biasp[col0 + wn * 64 + nt * 16 + rr];
  const float bscale = (SPLITK == 1 || kc == 0) ? 1.f : 0.f;

  if constexpr (OUTMODE == 4) {
    // fused router score: partial[row][xi2][e] = sum_{c in 64-col chunk}
    // relu(h[row][c]) * rw2[c][e].  xi2 = (col0>>6)+wn; waves wn=0/1 cover
    // disjoint 64-col halves -> disjoint xi2.  All 16 lanes of a q-group
    // butterfly-reduce over rr; lane rr==0 stores 8 floats.
    const float* rw2p = slot_gate;           // repurposed: rw2 [DFF][8]
    float4 wa[4], wb[4];
    #pragma unroll
    for (int nt = 0; nt < 4; nt++) {
      int c = col0 + wn * 64 + nt * 16 + rr;
      wa[nt] = *(const float4*)(rw2p + (size_t)c * 8);
      wb[nt] = *(const float4*)(rw2p + (size_t)c * 8 + 4);
    }
    float* Ps = (float*)Cout;
    const int xi2 = (col0 >> 6) + wn;
    #pragma unroll
    for (int mt = 0; mt < 4; mt++) {
      #pragma unroll
      for (int i = 0; i < 4; i++) {
        float4 sA = {0.f, 0.f, 0.f, 0.f}, sB = {0.f, 0.f, 0.f, 0.f};
        #pragma unroll
        for (int nt = 0; nt < 4; nt++) {
          float v = acc[mt][nt][i] + bv[nt];
          if (RELU) v = fmaxf(v, 0.f);
          sA.x += v * wa[nt].x; sA.y += v * wa[nt].y;
          sA.z += v * wa[nt].z; sA.w += v * wa[nt].w;
          sB.x += v * wb[nt].x; sB.y += v * wb[nt].y;
          sB.z += v * wb[nt].z; sB.w += v * wb[nt].w;
        }
        #pragma unroll
        for (int o = 1; o <= 8; o <<= 1) {   // reduce over rr (16-lane group)
          sA.x += __shfl_xor(sA.x, o); sA.y += __shfl_xor(sA.y, o);
          sA.z += __shfl_xor(sA.z, o); sA.w += __shfl_xor(sA.w, o);
          sB.x += __shfl_xor(sB.x, o); sB.y += __shfl_xor(sB.y, o);
          sB.z += __shfl_xor(sB.z, o); sB.w += __shfl_xor(sB.w, o);
        }
        if (rr == 0) {
          int row = row0 + wm * 64 + mt * 16 + q * 4 + i;
          float* p = Ps + ((size_t)row * 64 + xi2) * 8;
          *(float4*)p       = sA;
          *(float4*)(p + 4) = sB;
        }
      }
    }
  } else {
    #pragma unroll
    for (int mt = 0; mt < 4; mt++) {
      #pragma unroll
      for (int i = 0; i < 4; i++) {
        int r_loc = row0 + wm * 64 + mt * 16 + q * 4 + i;
        if (r_loc < m_cnt) {
          int slot = m_base + r_loc;
          float g = 1.f;
          if (OUTMODE == 3) g = slot_gate[slot];
          #pragma unroll
          for (int nt = 0; nt < 4; nt++) {
            float v = acc[mt][nt][i] + bscale * bv[nt];
            if (RELU) v = fmaxf(v, 0.f);
            int c = col0 + wn * 64 + nt * 16 + rr;
            if (OUTMODE == 0)      ((float*)Cout)[(size_t)slot * N + c]    = v;
            else if (OUTMODE == 1) ((ushort_t*)Cout)[(size_t)slot * N + c] = f2bf(v);
            else ((float*)Cout)[((size_t)kc * SLOTS + slot) * N + c] = g * v;
          }
        }
      }
    }
  }
}

// score[t][e] = sum_xi2 Ps[t][xi2][e] + rb2[e]; top-2 + softmax gates + counts.
// One wave per token; lane l holds chunk xi2=l (coalesced 2KB row read).
__global__ void router_reduce(const float* __restrict__ Ps, const float* __restrict__ rb2,
                              int* __restrict__ topi, float* __restrict__ gates,
                              int* __restrict__ counts)
{
  int t = blockIdx.x * 4 + (threadIdx.x >> 6);
  if (t >= TOKENS) return;
  int lane = threadIdx.x & 63;
  const float* pt = Ps + (size_t)t * 512;
  float4 v0 = *(const float4*)(pt + lane * 8);
  float4 v1 = *(const float4*)(pt + lane * 8 + 4);
  #pragma unroll
  for (int o = 1; o <= 32; o <<= 1) {       // reduce over the 64 chunks
    v0.x += __shfl_xor(v0.x, o); v0.y += __shfl_xor(v0.y, o);
    v0.z += __shfl_xor(v0.z, o); v0.w += __shfl_xor(v0.w, o);
    v1.x += __shfl_xor(v1.x, o); v1.y += __shfl_xor(v1.y, o);
    v1.z += __shfl_xor(v1.z, o); v1.w += __shfl_xor(v1.w, o);
  }
  if (lane == 0) {
    float s[8] = {v0.x + rb2[0], v0.y + rb2[1], v0.z + rb2[2], v0.w + rb2[3],
                  v1.x + rb2[4], v1.y + rb2[5], v1.z + rb2[6], v1.w + rb2[7]};
    int i0 = 0;
    #pragma unroll
    for (int e = 1; e < 8; e++) if (s[e] > s[i0]) i0 = e;   // ties -> lower idx (jax)
    int i1 = (i0 == 0) ? 1 : 0;
    #pragma unroll
    for (int e = 0; e < 8; e++) if (e != i0 && s[e] > s[i1]) i1 = e;
    float ex = __expf(s[i1] - s[i0]);
    float g0 = 1.f / (1.f + ex);
    float g1 = ex / (1.f + ex);
    topi[t * 2] = i0; topi[t * 2 + 1] = i1;
    gates[t * 2] = g0; gates[t * 2 + 1] = g1;
    atomicAdd(&counts[i0], 1);
    atomicAdd(&counts[i1], 1);
  }
}

// offsets + compacted live-tile list (tile index -> (expert, y-block))
__global__ void prefix_off(const int* __restrict__ counts, int* __restrict__ off,
                           int* __restrict__ tile_e, int* __restrict__ tile_y)
{
  if (threadIdx.x == 0) {
    int a = 0, t = 0;
    for (int e = 0; e < NEXP; e++) {
      off[e] = a;
      int c = counts[e]; a += c;
      int ty = (c + 127) >> 7;
      for (int y = 0; y < ty; y++) { tile_e[t] = e; tile_y[t] = y; t++; }
    }
    off[NEXP] = a;
    for (; t < TMAX; t++) { tile_e[t] = -1; tile_y[t] = 0; }
  }
}

__global__ void assign_slots(const int* __restrict__ topi, const float* __restrict__ gates,
                             const int* __restrict__ off, int* __restrict__ cursors,
                             int* __restrict__ slot_token, float* __restrict__ slot_gate,
                             int* __restrict__ tok_slot)
{
  int t = blockIdx.x * blockDim.x + threadIdx.x;
  if (t >= TOKENS) return;
  #pragma unroll
  for (int k = 0; k < 2; k++) {
    int e = topi[t * 2 + k];
    int p = atomicAdd(&cursors[e], 1);
    int s = off[e] + p;
    slot_token[s] = t;
    slot_gate[s]  = gates[t * 2 + k];
    tok_slot[t * 2 + k] = s;
  }
}

// out[t] = sum over {2 slots} x {2 k-chunks} of gated partials (gate/bias folded)
__global__ void combine_out(const float* __restrict__ Ys, const int* __restrict__ tok_slot,
                            float* __restrict__ out)
{
  int t = blockIdx.x;
  int d = threadIdx.x * 4;
  int s0 = tok_slot[t * 2], s1 = tok_slot[t * 2 + 1];
  float4 a = *(const float4*)(Ys + (size_t)s0 * EMBED + d);
  float4 b = *(const float4*)(Ys + ((size_t)SLOTS + s0) * EMBED + d);
  float4 c = *(const float4*)(Ys + (size_t)s1 * EMBED + d);
  float4 e = *(const float4*)(Ys + ((size_t)SLOTS + s1) * EMBED + d);
  float4 o;
  o.x = (a.x + b.x) + (c.x + e.x);
  o.y = (a.y + b.y) + (c.y + e.y);
  o.z = (a.z + b.z) + (c.z + e.z);
  o.w = (a.w + b.w) + (c.w + e.w);
  *(float4*)(out + (size_t)t * EMBED + d) = o;
}

extern "C" void kernel_launch(void* const* d_in, const int* in_sizes, int n_in,
                              void* d_out, int out_size, void* d_ws, size_t ws_size,
                              hipStream_t stream)
{
  const float* x   = (const float*)d_in[0];
  const float* rw1 = (const float*)d_in[1];
  const float* rb1 = (const float*)d_in[2];
  const float* rw2 = (const float*)d_in[3];
  const float* rb2 = (const float*)d_in[4];
  const float* W1  = (const float*)d_in[5];
  const float* b1  = (const float*)d_in[6];
  const float* W2  = (const float*)d_in[7];
  const float* b2  = (const float*)d_in[8];
  float* out = (float*)d_out;
  char* ws = (char*)d_ws;

  // Regions (all 33.5 MB), disjoint lifetimes within each:
  // A: RW1t [4096][3072] bf16 (router) -> WT = 4-expert W1t/W2t halves [n][k] bf16
  // B: Hs [4096][4096] bf16 (GEMM1 out; h deleted this round)
  // C: Xhl [2048][2048] bf16           -> Ys [2][4096][1024] f32 (GEMM2 partials)
  // Ps [2048][64][8] f32 (4MB) lives past the regions. Peak ~105MB (<109 proven).
  const size_t SZ_R = (size_t)4096 * 4096 * 2;   // 33.5 MB

  ushort_t* RW1t = (ushort_t*)ws;                 // region A
  ushort_t* WT   = (ushort_t*)ws;
  ushort_t* Hs   = (ushort_t*)(ws + SZ_R);        // region B
  ushort_t* Xhl  = (ushort_t*)(ws + 2 * SZ_R);    // region C
  float*    Ys   = (float*)(ws + 2 * SZ_R);
  char* ps = ws + 3 * SZ_R;
  float* Ps         = (float*)ps;  ps += (size_t)TOKENS * 512 * 4;  // 4MB
  int*   topi       = (int*)ps;    ps += TOKENS * 2 * 4;
  float* gates      = (float*)ps;  ps += TOKENS * 2 * 4;
  int*   tok_slot   = (int*)ps;    ps += TOKENS * 2 * 4;
  int*   slot_token = (int*)ps;    ps += SLOTS * 4;
  float* slot_gate  = (float*)ps;  ps += SLOTS * 4;
  int*   counts     = (int*)ps;    ps += 256;
  int*   cursors    = (int*)ps;    ps += 256;
  int*   off        = (int*)ps;    ps += 256;
  int*   tile_e     = (int*)ps;    ps += 256;
  int*   tile_y     = (int*)ps;    ps += 256;

  zero_small<<<1, 64, 0, stream>>>(counts, cursors);
  split_xhl<<<TOKENS, 256, 0, stream>>>(x, Xhl);

  // RW1t [n=4096][k'=3072] = [wh | wh | wl] transposed from rw1 [1024][4096]
  transp_conv<<<dim3(64, 16, 1), 256, 0, stream>>>(rw1, RW1t, DFF, 3072, 0, 0, 0,    0);
  transp_conv<<<dim3(64, 16, 1), 256, 0, stream>>>(rw1, RW1t, DFF, 3072, 0, 0, 1024, 0);
  transp_conv<<<dim3(64, 16, 1), 256, 0, stream>>>(rw1, RW1t, DFF, 3072, 0, 0, 2048, 1);

  // Router GEMM with fused score partials: Ps[t][xi2][e] (h never materialized)
  gemm_kernel<1, 4, true, false, 1, 32>
      <<<dim3(32, 16, 1), 256, 0, stream>>>(Xhl, RW1t, rb1, Ps, rw2, nullptr,
                                            nullptr, nullptr, nullptr, 0, NEXP,
                                            TOKENS, DFF, 3072);
  router_reduce<<<512, 256, 0, stream>>>(Ps, rb2, topi, gates, counts);
  prefix_off  <<<1, 64, 0, stream>>>(counts, off, tile_e, tile_y);
  assign_slots<<<8, 256, 0, stream>>>(topi, gates, off, cursors, slot_token, slot_gate, tok_slot);

  const long W1ES = (long)EMBED * DFF;   // floats per expert
  const long W2ES = (long)DFF * EMBED;

  for (int half = 0; half < 2; half++) {
    int e0 = half * 4;
    // WT <- bf16 W1[e0..e0+3]^T  : [k=1024][n=4096] -> [n=4096][k=1024]
    transp_conv<<<dim3(64, 16, 4), 256, 0, stream>>>(W1 + (size_t)e0 * W1ES, WT,
        DFF, EMBED, W1ES, W1ES, 0, 0);
    // GEMM1: Hs[slot] = relu(xh[token(slot)] @ W1[e] + b1[e]), bf16 out
    gemm_kernel<2, 1, true, true, 1, 32>
        <<<dim3(32 * TMAX, 1, 1), 256, 0, stream>>>(Xhl, WT, b1, Hs,
            nullptr, slot_token, off, tile_e, tile_y, e0, e0 + 4, 0, DFF, EMBED);
  }
  for (int half = 0; half < 2; half++) {
    int e0 = half * 4;
    // WT <- bf16 W2[e0..e0+3]^T  : [k=4096][n=1024] -> [n=1024][k=4096]
    transp_conv<<<dim3(16, 64, 4), 256, 0, stream>>>(W2 + (size_t)e0 * W2ES, WT,
        EMBED, DFF, W2ES, W2ES, 0, 0);
    // GEMM2: Ys[kc][slot] = gate*(Hs @ W2[e] kc-chunk + [kc==0]*b2[e]), f32 partials
    gemm_kernel<0, 3, false, true, 2, 8>
        <<<dim3(8 * 2 * TMAX, 1, 1), 256, 0, stream>>>(Hs, WT, b2, Ys,
            slot_gate, nullptr, off, tile_e, tile_y, e0, e0 + 4, 0, EMBED, DFF);
  }

  combine_out<<<TOKENS, 256, 0, stream>>>(Ys, tok_slot, out);
}